// Round 7
// baseline (2241.968 us; speedup 1.0000x reference)
//
#include <hip/hip_runtime.h>
#include <hip/hip_bf16.h>

// FilterModule: 7x MHA fusion pipeline, bf16 MFMA + flash attention v6.
// v6: m214-style attn — 32x32x16 MFMA, swapped QK^T (lane owns a q-row),
// in-register softmax, P->A-frag via one lane^32 half-swap, KVB=32 dbuf,
// 4-wave/256-thr blocks (2 blocks/CU). Split-bf16 weight GEMMs unchanged.

typedef __attribute__((ext_vector_type(8))) short short8;
typedef __attribute__((ext_vector_type(4))) float f32x4;
typedef __attribute__((ext_vector_type(16))) float f32x16;
typedef unsigned long long ull;

namespace {
constexpr int NTOK = 4096;
constexpr int EMB  = 1024;
constexpr int QTY  = 512;
}

__device__ __forceinline__ float bf2f(unsigned short u) {
    union { float f; unsigned int i; } x; x.i = ((unsigned int)u) << 16; return x.f;
}
__device__ __forceinline__ unsigned short f2bf(float f) {
    union { float f; unsigned int i; } x; x.f = f;
    unsigned int r = x.i + 0x7fffu + ((x.i >> 16) & 1u);
    return (unsigned short)(r >> 16);
}
__device__ __forceinline__ unsigned int cvt_pk_bf16(float a, float b) {
    unsigned int d;
    asm("v_cvt_pk_bf16_f32 %0, %1, %2" : "=v"(d) : "v"(a), "v"(b));
    return d;
}

#define GLOAD_LDS16(g, l) __builtin_amdgcn_global_load_lds( \
    (const __attribute__((address_space(1))) void*)(g),     \
    (__attribute__((address_space(3))) void*)(l), 16, 0, 0)

// ---------------------------------------------------------------------------
// MFMA GEMM (B^T layout): C[m][n] = alpha*sum_k A[m][k]*B[n][k] (+epilogue).
// 128x128 tile, BK=32, 256 thr. OUTM: 0=f32, 1=bf16, 2=split pair.
template<int SPLITS, int OUTM>
__global__ __launch_bounds__(256)
void gemm_mfma(const unsigned short* __restrict__ Ah, const unsigned short* __restrict__ Al,
               int lda, ull sAz,
               const unsigned short* __restrict__ Bh, const unsigned short* __restrict__ Bl,
               int ldb, ull sBz,
               void* __restrict__ Cp, void* __restrict__ Clp,
               int ldc, ull sCz,
               int K, float alpha, const float* __restrict__ bias,
               const unsigned short* __restrict__ resH, const unsigned short* __restrict__ resL,
               int resMode)
{
    constexpr int TSZ = 128 * 32;
    __shared__ unsigned short lds[(SPLITS == 3 ? 4 : 2) * TSZ];
    const int tid  = threadIdx.x;
    const int brow = blockIdx.y * 128;
    const int bcol = blockIdx.x * 128;
    const ull  z   = blockIdx.z;
    Ah += z * sAz; Bh += z * sBz;
    if constexpr (SPLITS == 3) { Al += z * sAz; Bl += z * sBz; }

    const int lane = tid & 63;
    const int wv = tid >> 6, wr = wv >> 1, wc = wv & 1;
    const int l15 = lane & 15, l4 = lane >> 4;

    f32x4 acc[4][4];
    #pragma unroll
    for (int m = 0; m < 4; ++m)
        #pragma unroll
        for (int n = 0; n < 4; ++n) acc[m][n] = (f32x4){0.f, 0.f, 0.f, 0.f};

    for (int k0 = 0; k0 < K; k0 += 32) {
        #pragma unroll
        for (int i = 0; i < 2; ++i) {
            int idx = tid + i * 256;
            int row = idx >> 2;
            int kc  = (idx & 3) ^ ((row >> 1) & 3);
            GLOAD_LDS16(Ah + (ull)(brow + row) * lda + k0 + kc * 8, &lds[idx * 8]);
            GLOAD_LDS16(Bh + (ull)(bcol + row) * ldb + k0 + kc * 8, &lds[TSZ + idx * 8]);
            if constexpr (SPLITS == 3) {
                GLOAD_LDS16(Al + (ull)(brow + row) * lda + k0 + kc * 8, &lds[2 * TSZ + idx * 8]);
                GLOAD_LDS16(Bl + (ull)(bcol + row) * ldb + k0 + kc * 8, &lds[3 * TSZ + idx * 8]);
            }
        }
        __syncthreads();

        short8 ah[4], bh[4], al2[4], bl2[4];
        #pragma unroll
        for (int m = 0; m < 4; ++m) {
            int rr = wr * 64 + m * 16 + l15;
            int sl = l4 ^ ((rr >> 1) & 3);
            int off = rr * 32 + sl * 8;
            ah[m] = *(const short8*)&lds[off];
            if constexpr (SPLITS == 3) al2[m] = *(const short8*)&lds[2 * TSZ + off];
        }
        #pragma unroll
        for (int n = 0; n < 4; ++n) {
            int rr = wc * 64 + n * 16 + l15;
            int sl = l4 ^ ((rr >> 1) & 3);
            int off = rr * 32 + sl * 8;
            bh[n] = *(const short8*)&lds[TSZ + off];
            if constexpr (SPLITS == 3) bl2[n] = *(const short8*)&lds[3 * TSZ + off];
        }
        #pragma unroll
        for (int m = 0; m < 4; ++m)
            #pragma unroll
            for (int n = 0; n < 4; ++n) {
                acc[m][n] = __builtin_amdgcn_mfma_f32_16x16x32_bf16(ah[m], bh[n], acc[m][n], 0, 0, 0);
                if constexpr (SPLITS == 3) {
                    acc[m][n] = __builtin_amdgcn_mfma_f32_16x16x32_bf16(ah[m], bl2[n], acc[m][n], 0, 0, 0);
                    acc[m][n] = __builtin_amdgcn_mfma_f32_16x16x32_bf16(al2[m], bh[n], acc[m][n], 0, 0, 0);
                }
            }
        __syncthreads();
    }

    float* Cf = (float*)Cp + z * sCz;
    unsigned short* Ch = (unsigned short*)Cp + z * sCz;
    unsigned short* Cl = (unsigned short*)Clp + z * sCz;
    const int rowB = brow + wr * 64 + l4 * 4;
    const int colB = bcol + wc * 64 + l15;
    #pragma unroll
    for (int n = 0; n < 4; ++n) {
        int col = colB + n * 16;
        float bv = bias ? bias[col] : 0.f;
        #pragma unroll
        for (int m = 0; m < 4; ++m) {
            #pragma unroll
            for (int r = 0; r < 4; ++r) {
                int row = rowB + m * 16 + r;
                ull ci = (ull)row * ldc + col;
                float v = acc[m][n][r] * alpha + bv;
                if (resMode == 1)      v += bf2f(resH[ci]) + bf2f(resL[ci]);
                else if (resMode == 2) v *= bf2f(resH[ci]) + bf2f(resL[ci]);
                if constexpr (OUTM == 0)      Cf[ci] = v;
                else if constexpr (OUTM == 1) Ch[ci] = f2bf(v);
                else {
                    unsigned short h = f2bf(v);
                    Ch[ci] = h;
                    Cl[ci] = f2bf(v - bf2f(h));
                }
            }
        }
    }
}

// ---------------------------------------------------------------------------
// Flash attention v6. QKV [4096][3072] bf16; VT [1024][4096] bf16 (V^T).
// 4 waves x 32 q-rows = 128 q/block; grid (32 qt, 4 sp, 4 h); KVB=32 dbuf.
// Swapped QK^T with 32x32x16: lane q = lane&31 owns the P-row; softmax fully
// in-register; P->PV A-frag via one shfl_xor(32) half-swap.
__global__ __launch_bounds__(256, 1)
void flash_attn(const unsigned short* __restrict__ QKV,
                const unsigned short* __restrict__ VT,
                unsigned short* __restrict__ Opart, float* __restrict__ ml)
{
    constexpr int KVB = 32;
    constexpr int NTILE = 1024 / KVB;            // 32
    __shared__ unsigned short Kt[2][KVB * 256];  // 2 x 16 KB
    __shared__ unsigned short Vt[2][256 * KVB];  // 2 x 16 KB

    const int tid = threadIdx.x;
    const int w = tid >> 6, lane = tid & 63;
    const int l31 = lane & 31;
    const int hl  = lane >> 5;
    const int qt = blockIdx.x, sp = blockIdx.y, h = blockIdx.z;
    const int qbase = qt * 128 + w * 32;
    const int kv0 = sp * 1024;

    // Q B-fragments: qreg[ks], lane: q = qbase+l31, k = ks*16 + hl*8 + j.
    // Pre-scaled by 1/sqrt(d)=1/16 (exact in bf16).
    short8 qreg[16];
    {
        const unsigned short* qp = QKV + (ull)(qbase + l31) * 3072 + h * 256 + hl * 8;
        #pragma unroll
        for (int ks = 0; ks < 16; ++ks) {
            short8 x = *(const short8*)&qp[ks * 16];
            #pragma unroll
            for (int j = 0; j < 8; ++j)
                x[j] = (short)f2bf(bf2f((unsigned short)x[j]) * 0.0625f);
            qreg[ks] = x;
        }
    }

    // O accumulators: 8 d-blocks of 32; C layout row q=(r&3)+8*(r>>2)+4*hl, col d
    f32x16 oacc[8];
    #pragma unroll
    for (int db = 0; db < 8; ++db)
        #pragma unroll
        for (int r = 0; r < 16; ++r) oacc[db][r] = 0.f;
    float m_r = -1e30f, l_r = 0.f;

    auto stage = [&](int t, int buf) {
        int base = kv0 + t * KVB;
        #pragma unroll
        for (int i = 0; i < 4; ++i) {     // K: 32 rows x 32 chunks(16B), src-swizzled
            int s = tid + i * 256;
            int r = s >> 5, c = s & 31;
            int c0 = c ^ (r & 7);
            GLOAD_LDS16(QKV + (ull)(base + r) * 3072 + 1024 + h * 256 + c0 * 8,
                        &Kt[buf][s * 8]);
        }
        #pragma unroll
        for (int i = 0; i < 4; ++i) {     // V^T: 256 rows x 4 chunks, src-swizzled
            int s = tid + i * 256;
            int r = s >> 2, c = s & 3;
            int c0 = c ^ (r & 3);
            GLOAD_LDS16(VT + (ull)(h * 256 + r) * 4096 + base + c0 * 8,
                        &Vt[buf][s * 8]);
        }
    };

    stage(0, 0);
    for (int t = 0; t < NTILE; ++t) {
        if (t + 1 < NTILE) {
            stage(t + 1, (t + 1) & 1);
            asm volatile("s_waitcnt vmcnt(8)");
        } else {
            asm volatile("s_waitcnt vmcnt(0)");
        }
        __builtin_amdgcn_s_barrier();

        const unsigned short* Kb = Kt[t & 1];
        const unsigned short* Vb = Vt[t & 1];

        // QK^T (swapped): S^T[kv][q]; lane holds q=l31, kv=(r&3)+8*(r>>2)+4*hl
        f32x16 sacc;
        #pragma unroll
        for (int r = 0; r < 16; ++r) sacc[r] = 0.f;
        __builtin_amdgcn_s_setprio(1);
        #pragma unroll
        for (int ks = 0; ks < 16; ++ks) {
            int c = (ks * 2 + hl) ^ (l31 & 7);
            short8 kf = *(const short8*)&Kb[l31 * 256 + c * 8];
            sacc = __builtin_amdgcn_mfma_f32_32x32x16_bf16(kf, qreg[ks], sacc, 0, 0, 0);
        }
        __builtin_amdgcn_s_setprio(0);

        // in-register online softmax (row = my q; merge halves via shfl_xor 32)
        float tm = sacc[0];
        #pragma unroll
        for (int r = 1; r < 16; ++r) tm = fmaxf(tm, sacc[r]);
        tm = fmaxf(tm, __shfl_xor(tm, 32));

        if (!__all(tm <= m_r + 5.545f)) {   // defer-max
            float mnew = fmaxf(m_r, tm);
            float corr = __expf(m_r - mnew);
            float c16[16];
            #pragma unroll
            for (int r = 0; r < 16; ++r)
                c16[r] = __shfl(corr, (r & 3) + 8 * (r >> 2) + 4 * hl);
            #pragma unroll
            for (int db = 0; db < 8; ++db)
                #pragma unroll
                for (int r = 0; r < 16; ++r) oacc[db][r] *= c16[r];
            l_r *= corr;
            m_r = mnew;
        }

        float ls = 0.f;
        #pragma unroll
        for (int r = 0; r < 16; ++r) {
            float e = __expf(sacc[r] - m_r);
            sacc[r] = e; ls += e;
        }
        ls += __shfl_xor(ls, 32);
        l_r += ls;

        // P -> A-frag (half-swap) + PV per 16-kv step
        #pragma unroll
        for (int ks = 0; ks < 2; ++ks) {
            unsigned int u0 = cvt_pk_bf16(sacc[8 * ks + 0], sacc[8 * ks + 1]);
            unsigned int u1 = cvt_pk_bf16(sacc[8 * ks + 2], sacc[8 * ks + 3]);
            unsigned int u2 = cvt_pk_bf16(sacc[8 * ks + 4], sacc[8 * ks + 5]);
            unsigned int u3 = cvt_pk_bf16(sacc[8 * ks + 6], sacc[8 * ks + 7]);
            unsigned int s0 = hl ? u0 : u2;
            unsigned int s1 = hl ? u1 : u3;
            unsigned int r0 = (unsigned int)__shfl_xor((int)s0, 32);
            unsigned int r1 = (unsigned int)__shfl_xor((int)s1, 32);
            union { unsigned int u[4]; short8 s8; } pf;
            pf.u[0] = hl ? r0 : u0;
            pf.u[1] = hl ? r1 : u1;
            pf.u[2] = hl ? u2 : r0;
            pf.u[3] = hl ? u3 : r1;

            __builtin_amdgcn_s_setprio(1);
            #pragma unroll
            for (int db = 0; db < 8; ++db) {
                int d = db * 32 + l31;
                int c = (ks * 2 + hl) ^ (d & 3);
                short8 vf = *(const short8*)&Vb[d * 32 + c * 8];
                oacc[db] = __builtin_amdgcn_mfma_f32_32x32x16_bf16(pf.s8, vf, oacc[db], 0, 0, 0);
            }
            __builtin_amdgcn_s_setprio(0);
        }
        __builtin_amdgcn_s_barrier();
    }

    // epilogue: normalized O (bf16) + (m,l)
    unsigned short* Ob = Opart + (ull)(sp * 4 + h) * NTOK * 256;
    float inv = 1.f / l_r;
    float i16[16];
    #pragma unroll
    for (int r = 0; r < 16; ++r)
        i16[r] = __shfl(inv, (r & 3) + 8 * (r >> 2) + 4 * hl);
    #pragma unroll
    for (int db = 0; db < 8; ++db) {
        int d = db * 32 + l31;
        #pragma unroll
        for (int r = 0; r < 16; ++r) {
            int q = qbase + (r & 3) + 8 * (r >> 2) + 4 * hl;
            Ob[(ull)q * 256 + d] = f2bf(oacc[db][r] * i16[r]);
        }
    }
    if (lane < 32) {
        float2* mlp = (float2*)ml + (ull)(sp * 4 + h) * NTOK + qbase + lane;
        *mlp = make_float2(m_r, l_r);
    }
}

// ---------------------------------------------------------------------------
// merge 4 KV-split partials -> att split pair. block = one q row (4h x 256d).
__global__ __launch_bounds__(256)
void flash_combine(const unsigned short* __restrict__ Opart, const float* __restrict__ ml,
                   unsigned short* __restrict__ attH, unsigned short* __restrict__ attL)
{
    const int q = blockIdx.x;
    const int t = threadIdx.x;
    const int h = t >> 6, d4 = (t & 63) * 4;

    float2 m4[4]; float ms = -1e30f;
    #pragma unroll
    for (int s = 0; s < 4; ++s) {
        m4[s] = ((const float2*)ml)[(ull)(s * 4 + h) * NTOK + q];
        ms = fmaxf(ms, m4[s].x);
    }
    float wt[4], denom = 0.f;
    #pragma unroll
    for (int s = 0; s < 4; ++s) {
        wt[s] = __expf(m4[s].x - ms) * m4[s].y;
        denom += wt[s];
    }
    float inv = 1.f / denom;
    float acc[4] = { 0.f, 0.f, 0.f, 0.f };
    #pragma unroll
    for (int s = 0; s < 4; ++s) {
        ushort4 o = *(const ushort4*)&Opart[((ull)(s * 4 + h) * NTOK + q) * 256 + d4];
        acc[0] += wt[s] * bf2f(o.x); acc[1] += wt[s] * bf2f(o.y);
        acc[2] += wt[s] * bf2f(o.z); acc[3] += wt[s] * bf2f(o.w);
    }
    ull ai = (ull)q * EMB + h * 256 + d4;
    ushort4 ho, lo;
    float v0 = acc[0] * inv, v1 = acc[1] * inv, v2 = acc[2] * inv, v3 = acc[3] * inv;
    ho.x = f2bf(v0); lo.x = f2bf(v0 - bf2f(ho.x));
    ho.y = f2bf(v1); lo.y = f2bf(v1 - bf2f(ho.y));
    ho.z = f2bf(v2); lo.z = f2bf(v2 - bf2f(ho.z));
    ho.w = f2bf(v3); lo.w = f2bf(v3 - bf2f(ho.w));
    *(ushort4*)&attH[ai] = ho;
    *(ushort4*)&attL[ai] = lo;
}

// ---------------------------------------------------------------------------
template<bool F32IN>
__global__ __launch_bounds__(256)
void l2norm_rows(const float* __restrict__ inF, const unsigned short* __restrict__ inH,
                 const unsigned short* __restrict__ inL,
                 unsigned short* __restrict__ oH, unsigned short* __restrict__ oL)
{
    const ull row = blockIdx.x;
    const int t = threadIdx.x;
    const int lane = t & 63, wid = t >> 6;
    __shared__ float red[4];

    float v[4];
    if constexpr (F32IN) {
        float4 x = *(const float4*)&inF[row * EMB + t * 4];
        v[0] = x.x; v[1] = x.y; v[2] = x.z; v[3] = x.w;
    } else {
        ushort4 hh = *(const ushort4*)&inH[row * EMB + t * 4];
        ushort4 ll = *(const ushort4*)&inL[row * EMB + t * 4];
        v[0] = bf2f(hh.x) + bf2f(ll.x); v[1] = bf2f(hh.y) + bf2f(ll.y);
        v[2] = bf2f(hh.z) + bf2f(ll.z); v[3] = bf2f(hh.w) + bf2f(ll.w);
    }
    float ss = v[0] * v[0] + v[1] * v[1] + v[2] * v[2] + v[3] * v[3];
    #pragma unroll
    for (int o = 32; o > 0; o >>= 1) ss += __shfl_down(ss, o);
    if (lane == 0) red[wid] = ss;
    __syncthreads();
    ss = red[0] + red[1] + red[2] + red[3];

    float inv = 1.f / fmaxf(sqrtf(ss), 1e-8f);
    ushort4 ho, lo;
    float s0 = v[0] * inv, s1 = v[1] * inv, s2 = v[2] * inv, s3 = v[3] * inv;
    ho.x = f2bf(s0); lo.x = f2bf(s0 - bf2f(ho.x));
    ho.y = f2bf(s1); lo.y = f2bf(s1 - bf2f(ho.y));
    ho.z = f2bf(s2); lo.z = f2bf(s2 - bf2f(ho.z));
    ho.w = f2bf(s3); lo.w = f2bf(s3 - bf2f(ho.w));
    *(ushort4*)&oH[row * EMB + t * 4] = ho;
    *(ushort4*)&oL[row * EMB + t * 4] = lo;
}

__global__ __launch_bounds__(256)
void add_pos_pair(const float* __restrict__ in, const float* __restrict__ pos,
                  unsigned short* __restrict__ oH, unsigned short* __restrict__ oL)
{
    ull i = ((ull)blockIdx.x * 256 + threadIdx.x) * 4;
    float4 a = *(const float4*)&in[i];
    float4 p = *(const float4*)&pos[(int)(i & (EMB - 1))];
    float w[4] = { a.x + p.x, a.y + p.y, a.z + p.z, a.w + p.w };
    ushort4 ho, lo;
    ho.x = f2bf(w[0]); lo.x = f2bf(w[0] - bf2f(ho.x));
    ho.y = f2bf(w[1]); lo.y = f2bf(w[1] - bf2f(ho.y));
    ho.z = f2bf(w[2]); lo.z = f2bf(w[2] - bf2f(ho.z));
    ho.w = f2bf(w[3]); lo.w = f2bf(w[3] - bf2f(ho.w));
    *(ushort4*)&oH[i] = ho;
    *(ushort4*)&oL[i] = lo;
}

__global__ __launch_bounds__(256)
void split_pair(const float* __restrict__ in, unsigned short* __restrict__ oH,
                unsigned short* __restrict__ oL)
{
    ull i = ((ull)blockIdx.x * 256 + threadIdx.x) * 4;
    float4 a = *(const float4*)&in[i];
    float w[4] = { a.x, a.y, a.z, a.w };
    ushort4 ho, lo;
    ho.x = f2bf(w[0]); lo.x = f2bf(w[0] - bf2f(ho.x));
    ho.y = f2bf(w[1]); lo.y = f2bf(w[1] - bf2f(ho.y));
    ho.z = f2bf(w[2]); lo.z = f2bf(w[2] - bf2f(ho.z));
    ho.w = f2bf(w[3]); lo.w = f2bf(w[3] - bf2f(ho.w));
    *(ushort4*)&oH[i] = ho;
    *(ushort4*)&oL[i] = lo;
}

// transpose bf16 [4096][ld] block cols -> out [1024][4096]
__global__ __launch_bounds__(256)
void transpose_bf16(const unsigned short* __restrict__ in, int ld,
                    unsigned short* __restrict__ out) {
    __shared__ unsigned short tile[64][65];
    const int bx = blockIdx.x * 64;
    const int by = blockIdx.y * 64;
    const int t = threadIdx.x;
    #pragma unroll
    for (int i = 0; i < 16; ++i) {
        int idx = i * 256 + t;
        int r = idx >> 6, c = idx & 63;
        tile[r][c] = in[(ull)(by + r) * ld + bx + c];
    }
    __syncthreads();
    #pragma unroll
    for (int i = 0; i < 16; ++i) {
        int idx = i * 256 + t;
        int r = idx >> 6, c = idx & 63;
        out[(ull)(bx + r) * 4096 + by + c] = tile[c][r];
    }
}

// ---------------------------------------------------------------------------
namespace {

template<int S, int O>
inline void G(dim3 grid,
              const unsigned short* Ah, const unsigned short* Al, int lda, ull sAz,
              const unsigned short* Bh, const unsigned short* Bl, int ldb, ull sBz,
              void* Ch, void* Cl, int ldc, ull sCz,
              int K, float alpha, const float* bias,
              const unsigned short* rh, const unsigned short* rl, int rm, hipStream_t st)
{
    gemm_mfma<S, O><<<grid, dim3(256), 0, st>>>(Ah, Al, lda, sAz, Bh, Bl, ldb, sBz,
                                                Ch, Cl, ldc, sCz, K, alpha, bias, rh, rl, rm);
}

struct Bufs {
    unsigned short *Ph[6], *Pl[6];
    unsigned short *ATTh, *ATTl, *QKV, *VT, *Wih, *Wil, *Woh, *Wol, *Opart;
    float *ml;
};

void run_mha(const unsigned short* qh, const unsigned short* ql,
             const unsigned short* kh, const unsigned short* kl,
             const float* in_w, const float* in_b,
             const float* out_w, const float* out_b,
             unsigned short* dsth, unsigned short* dstl,
             const unsigned short* resh, const unsigned short* resl, int resMode,
             const Bufs& B, bool convW, hipStream_t s)
{
    const ull EE = (ull)EMB * EMB;
    if (convW) {
        split_pair<<<3 * EE / 1024, 256, 0, s>>>(in_w, B.Wih, B.Wil);
        split_pair<<<EE / 1024, 256, 0, s>>>(out_w, B.Woh, B.Wol);
    }
    // Q proj -> QKV[:, 0:1024]; fused KV proj -> QKV[:, 1024:3072]
    G<3, 1>(dim3(8, 32), qh, ql, EMB, 0, B.Wih, B.Wil, EMB, 0,
            B.QKV, nullptr, 3072, 0, EMB, 1.f, in_b, nullptr, nullptr, 0, s);
    G<3, 1>(dim3(16, 32), kh, kl, EMB, 0, B.Wih + EE, B.Wil + EE, EMB, 0,
            B.QKV + 1024, nullptr, 3072, 0, EMB, 1.f, in_b + EMB, nullptr, nullptr, 0, s);
    transpose_bf16<<<dim3(16, 64), 256, 0, s>>>(B.QKV + 2048, 3072, B.VT);

    flash_attn<<<dim3(32, 4, 4), 256, 0, s>>>(B.QKV, B.VT, B.Opart, B.ml);
    flash_combine<<<NTOK, 256, 0, s>>>(B.Opart, B.ml, B.ATTh, B.ATTl);

    G<3, 2>(dim3(EMB / 128, NTOK / 128), B.ATTh, B.ATTl, EMB, 0, B.Woh, B.Wol, EMB, 0,
            dsth, dstl, EMB, 0, EMB, 1.f, out_b, resh, resl, resMode, s);
}

} // namespace

extern "C" void kernel_launch(void* const* d_in, const int* in_sizes, int n_in,
                              void* d_out, int out_size, void* d_ws, size_t ws_size,
                              hipStream_t stream) {
    const float* local_feat  = (const float*)d_in[0];
    const float* global_feat = (const float*)d_in[1];
    const float* text_feat   = (const float*)d_in[2];
    const float* pos_l       = (const float*)d_in[3];
    const float* pos_g       = (const float*)d_in[4];
    const float* fc_w        = (const float*)d_in[5];
    const float* fc_b        = (const float*)d_in[6];
    const float* lg_in_w     = (const float*)d_in[7];
    const float* lg_in_b     = (const float*)d_in[8];
    const float* lg_out_w    = (const float*)d_in[9];
    const float* lg_out_b    = (const float*)d_in[10];
    const float* vt_in_w     = (const float*)d_in[11];
    const float* vt_in_b     = (const float*)d_in[12];
    const float* vt_out_w    = (const float*)d_in[13];
    const float* vt_out_b    = (const float*)d_in[14];
    const float* ml_in_w     = (const float*)d_in[15];
    const float* ml_in_b     = (const float*)d_in[16];
    const float* ml_out_w    = (const float*)d_in[17];
    const float* ml_out_b    = (const float*)d_in[18];
    float* out = (float*)d_out;

    const ull TE = (ull)NTOK * EMB;
    unsigned short* w = (unsigned short*)d_ws;
    Bufs B;
    for (int i = 0; i < 6; ++i) { B.Ph[i] = w + (2 * i) * TE; B.Pl[i] = w + (2 * i + 1) * TE; }
    B.ATTh = w + 12 * TE; B.ATTl = w + 13 * TE;
    B.QKV  = w + 14 * TE;               // 3 TE
    B.VT   = w + 17 * TE;               // 1 TE
    B.Opart = w + 18 * TE;              // 4 TE (bf16, 4 splits x 4 heads)
    B.ml    = (float*)(w + 22 * TE);    // 512 KB
    B.Wih = w + 26 * TE; B.Wil = B.Wih + 3 * (ull)EMB * EMB;
    B.Woh = B.Wil + 3 * (ull)EMB * EMB; B.Wol = B.Woh + (ull)EMB * EMB;

    add_pos_pair<<<TE / 1024, 256, 0, stream>>>(local_feat, pos_l, B.Ph[0], B.Pl[0]);
    add_pos_pair<<<TE / 1024, 256, 0, stream>>>(global_feat, pos_g, B.Ph[1], B.Pl[1]);

    // tf = text @ fc_w^T + fc_b -> P2 (text split staged in ATT pair)
    split_pair<<<TE / 1024, 256, 0, stream>>>(text_feat, B.ATTh, B.ATTl);
    split_pair<<<(ull)EMB * EMB / 1024, 256, 0, stream>>>(fc_w, B.Wih, B.Wil);
    G<3, 2>(dim3(EMB / 128, NTOK / 128), B.ATTh, B.ATTl, EMB, 0, B.Wih, B.Wil, EMB, 0,
            B.Ph[2], B.Pl[2], EMB, 0, EMB, 1.f, fc_b, nullptr, nullptr, 0, stream);

    run_mha(B.Ph[0], B.Pl[0], B.Ph[1], B.Pl[1], lg_in_w, lg_in_b, lg_out_w, lg_out_b,
            B.Ph[3], B.Pl[3], B.Ph[0], B.Pl[0], 1, B, true, stream);
    run_mha(B.Ph[2], B.Pl[2], B.Ph[0], B.Pl[0], vt_in_w, vt_in_b, vt_out_w, vt_out_b,
            B.Ph[4], B.Pl[4], B.Ph[0], B.Pl[0], 1, B, true, stream);
    run_mha(B.Ph[2], B.Pl[2], B.Ph[1], B.Pl[1], vt_in_w, vt_in_b, vt_out_w, vt_out_b,
            B.Ph[5], B.Pl[5], B.Ph[2], B.Pl[2], 1, B, false, stream);
    run_mha(B.Ph[3], B.Pl[3], B.Ph[5], B.Pl[5], ml_in_w, ml_in_b, ml_out_w, ml_out_b,
            B.Ph[0], B.Pl[0], nullptr, nullptr, 0, B, true, stream);
    run_mha(B.Ph[4], B.Pl[4], B.Ph[3], B.Pl[3], ml_in_w, ml_in_b, ml_out_w, ml_out_b,
            B.Ph[1], B.Pl[1], nullptr, nullptr, 0, B, false, stream);
    run_mha(B.Ph[1], B.Pl[1], B.Ph[0], B.Pl[0], ml_in_w, ml_in_b, ml_out_w, ml_out_b,
            B.Ph[3], B.Pl[3], nullptr, nullptr, 0, B, false, stream);
    run_mha(B.Ph[2], B.Pl[2], B.Ph[3], B.Pl[3], ml_in_w, ml_in_b, ml_out_w, ml_out_b,
            B.Ph[4], B.Pl[4], B.Ph[2], B.Pl[2], 2, B, false, stream);

    l2norm_rows<false><<<NTOK, 256, 0, stream>>>(nullptr, B.Ph[4], B.Pl[4], B.Ph[4], B.Pl[4]);
    l2norm_rows<true ><<<NTOK, 256, 0, stream>>>(local_feat, nullptr, nullptr, B.Ph[5], B.Pl[5]);

    G<3, 0>(dim3(QTY / 128, QTY / 128, 8),
            B.Ph[4], B.Pl[4], EMB, (ull)QTY * EMB,
            B.Ph[5], B.Pl[5], EMB, (ull)QTY * EMB,
            out, nullptr, QTY, (ull)QTY * QTY,
            EMB, 1.f, nullptr, nullptr, nullptr, 0, stream);
}

// Round 8
// 2051.109 us; speedup vs baseline: 1.0931x; 1.0931x over previous
//
#include <hip/hip_runtime.h>
#include <hip/hip_bf16.h>

// FilterModule: 7x MHA fusion pipeline, bf16 MFMA + flash attention v7.
// v7 = R3's measured-best flash structure (8 waves x 16q, KVB=64, 2-way split,
// shfl P-repack, VGPR ~96 no-spill) + normalized-bf16 Opart (half the partial
// traffic) + light 2-way combine. Split-bf16 weight GEMMs unchanged.

typedef __attribute__((ext_vector_type(8))) short short8;
typedef __attribute__((ext_vector_type(4))) float f32x4;
typedef unsigned long long ull;

namespace {
constexpr int NTOK = 4096;
constexpr int EMB  = 1024;
constexpr int QTY  = 512;
}

__device__ __forceinline__ float bf2f(unsigned short u) {
    union { float f; unsigned int i; } x; x.i = ((unsigned int)u) << 16; return x.f;
}
__device__ __forceinline__ unsigned short f2bf(float f) {
    union { float f; unsigned int i; } x; x.f = f;
    unsigned int r = x.i + 0x7fffu + ((x.i >> 16) & 1u);
    return (unsigned short)(r >> 16);
}

#define GLOAD_LDS16(g, l) __builtin_amdgcn_global_load_lds( \
    (const __attribute__((address_space(1))) void*)(g),     \
    (__attribute__((address_space(3))) void*)(l), 16, 0, 0)

// ---------------------------------------------------------------------------
// MFMA GEMM (B^T layout): C[m][n] = alpha*sum_k A[m][k]*B[n][k] (+epilogue).
// 128x128 tile, BK=32, 256 thr. OUTM: 0=f32, 1=bf16, 2=split pair.
template<int SPLITS, int OUTM>
__global__ __launch_bounds__(256)
void gemm_mfma(const unsigned short* __restrict__ Ah, const unsigned short* __restrict__ Al,
               int lda, ull sAz,
               const unsigned short* __restrict__ Bh, const unsigned short* __restrict__ Bl,
               int ldb, ull sBz,
               void* __restrict__ Cp, void* __restrict__ Clp,
               int ldc, ull sCz,
               int K, float alpha, const float* __restrict__ bias,
               const unsigned short* __restrict__ resH, const unsigned short* __restrict__ resL,
               int resMode)
{
    constexpr int TSZ = 128 * 32;
    __shared__ unsigned short lds[(SPLITS == 3 ? 4 : 2) * TSZ];
    const int tid  = threadIdx.x;
    const int brow = blockIdx.y * 128;
    const int bcol = blockIdx.x * 128;
    const ull  z   = blockIdx.z;
    Ah += z * sAz; Bh += z * sBz;
    if constexpr (SPLITS == 3) { Al += z * sAz; Bl += z * sBz; }

    const int lane = tid & 63;
    const int wv = tid >> 6, wr = wv >> 1, wc = wv & 1;
    const int l15 = lane & 15, l4 = lane >> 4;

    f32x4 acc[4][4];
    #pragma unroll
    for (int m = 0; m < 4; ++m)
        #pragma unroll
        for (int n = 0; n < 4; ++n) acc[m][n] = (f32x4){0.f, 0.f, 0.f, 0.f};

    for (int k0 = 0; k0 < K; k0 += 32) {
        #pragma unroll
        for (int i = 0; i < 2; ++i) {
            int idx = tid + i * 256;
            int row = idx >> 2;
            int kc  = (idx & 3) ^ ((row >> 1) & 3);
            GLOAD_LDS16(Ah + (ull)(brow + row) * lda + k0 + kc * 8, &lds[idx * 8]);
            GLOAD_LDS16(Bh + (ull)(bcol + row) * ldb + k0 + kc * 8, &lds[TSZ + idx * 8]);
            if constexpr (SPLITS == 3) {
                GLOAD_LDS16(Al + (ull)(brow + row) * lda + k0 + kc * 8, &lds[2 * TSZ + idx * 8]);
                GLOAD_LDS16(Bl + (ull)(bcol + row) * ldb + k0 + kc * 8, &lds[3 * TSZ + idx * 8]);
            }
        }
        __syncthreads();

        short8 ah[4], bh[4], al2[4], bl2[4];
        #pragma unroll
        for (int m = 0; m < 4; ++m) {
            int rr = wr * 64 + m * 16 + l15;
            int sl = l4 ^ ((rr >> 1) & 3);
            int off = rr * 32 + sl * 8;
            ah[m] = *(const short8*)&lds[off];
            if constexpr (SPLITS == 3) al2[m] = *(const short8*)&lds[2 * TSZ + off];
        }
        #pragma unroll
        for (int n = 0; n < 4; ++n) {
            int rr = wc * 64 + n * 16 + l15;
            int sl = l4 ^ ((rr >> 1) & 3);
            int off = rr * 32 + sl * 8;
            bh[n] = *(const short8*)&lds[TSZ + off];
            if constexpr (SPLITS == 3) bl2[n] = *(const short8*)&lds[3 * TSZ + off];
        }
        #pragma unroll
        for (int m = 0; m < 4; ++m)
            #pragma unroll
            for (int n = 0; n < 4; ++n) {
                acc[m][n] = __builtin_amdgcn_mfma_f32_16x16x32_bf16(ah[m], bh[n], acc[m][n], 0, 0, 0);
                if constexpr (SPLITS == 3) {
                    acc[m][n] = __builtin_amdgcn_mfma_f32_16x16x32_bf16(ah[m], bl2[n], acc[m][n], 0, 0, 0);
                    acc[m][n] = __builtin_amdgcn_mfma_f32_16x16x32_bf16(al2[m], bh[n], acc[m][n], 0, 0, 0);
                }
            }
        __syncthreads();
    }

    float* Cf = (float*)Cp + z * sCz;
    unsigned short* Ch = (unsigned short*)Cp + z * sCz;
    unsigned short* Cl = (unsigned short*)Clp + z * sCz;
    const int rowB = brow + wr * 64 + l4 * 4;
    const int colB = bcol + wc * 64 + l15;
    #pragma unroll
    for (int n = 0; n < 4; ++n) {
        int col = colB + n * 16;
        float bv = bias ? bias[col] : 0.f;
        #pragma unroll
        for (int m = 0; m < 4; ++m) {
            #pragma unroll
            for (int r = 0; r < 4; ++r) {
                int row = rowB + m * 16 + r;
                ull ci = (ull)row * ldc + col;
                float v = acc[m][n][r] * alpha + bv;
                if (resMode == 1)      v += bf2f(resH[ci]) + bf2f(resL[ci]);
                else if (resMode == 2) v *= bf2f(resH[ci]) + bf2f(resL[ci]);
                if constexpr (OUTM == 0)      Cf[ci] = v;
                else if constexpr (OUTM == 1) Ch[ci] = f2bf(v);
                else {
                    unsigned short h = f2bf(v);
                    Ch[ci] = h;
                    Cl[ci] = f2bf(v - bf2f(h));
                }
            }
        }
    }
}

// ---------------------------------------------------------------------------
// Flash attention v7 (R3 structure). QKV [4096][3072] bf16; VT [1024][4096].
// 8 warps x 16 q-rows; KV split 2-way across blockIdx.y; KVB=64 dbuf.
// Outputs normalized O (bf16) per split + (m,l).
__global__ __launch_bounds__(512)
void flash_attn(const unsigned short* __restrict__ QKV,
                const unsigned short* __restrict__ VT,
                unsigned short* __restrict__ Opart, float* __restrict__ ml)
{
    constexpr int KVB = 64;
    constexpr int NTILE = 2048 / KVB;   // 32 tiles per block
    __shared__ unsigned short Kt[2][KVB * 256];   // [kv][d], 16B-chunk-swizzled
    __shared__ unsigned short Vt[2][256 * KVB];   // [d][kv], swizzled

    const int tid = threadIdx.x;
    const int w = tid >> 6, lane = tid & 63;
    const int l15 = lane & 15, l4 = lane >> 4;
    const int qt = blockIdx.x, sp = blockIdx.y, h = blockIdx.z;
    const int qrow = qt * 128 + w * 16 + l15;
    const int kv0 = sp * 2048;

    // Q fragments in registers, pre-scaled by 1/sqrt(d)=1/16 (exact in bf16)
    short8 qreg[8];
    {
        const unsigned short* qp = QKV + (ull)qrow * 3072 + h * 256;
        #pragma unroll
        for (int c = 0; c < 8; ++c) {
            short8 x = *(const short8*)&qp[c * 32 + l4 * 8];
            #pragma unroll
            for (int j = 0; j < 8; ++j)
                x[j] = (short)f2bf(bf2f((unsigned short)x[j]) * 0.0625f);
            qreg[c] = x;
        }
    }

    f32x4 oacc[16];
    #pragma unroll
    for (int dn = 0; dn < 16; ++dn) oacc[dn] = (f32x4){0.f, 0.f, 0.f, 0.f};
    float m_r = -1e30f, l_r = 0.f;

    auto stage = [&](int t, int buf) {
        int base = kv0 + t * KVB;
        #pragma unroll
        for (int i = 0; i < 4; ++i) {       // K tile: 64 rows x 32 chunks
            int s = tid + i * 512;
            int r = s >> 5, c = s & 31;
            int c0 = c ^ (r & 7);
            GLOAD_LDS16(QKV + (ull)(base + r) * 3072 + 1024 + h * 256 + c0 * 8,
                        &Kt[buf][s * 8]);
        }
        #pragma unroll
        for (int i = 0; i < 4; ++i) {       // V^T tile: 256 rows x 8 chunks
            int s = tid + i * 512;
            int r = s >> 3, c = s & 7;
            int c0 = c ^ (r & 7);
            GLOAD_LDS16(VT + (ull)(h * 256 + r) * 4096 + base + c0 * 8,
                        &Vt[buf][s * 8]);
        }
    };

    stage(0, 0);
    for (int t = 0; t < NTILE; ++t) {
        if (t + 1 < NTILE) {
            stage(t + 1, (t + 1) & 1);
            asm volatile("s_waitcnt vmcnt(8)");
        } else {
            asm volatile("s_waitcnt vmcnt(0)");
        }
        __builtin_amdgcn_s_barrier();

        const unsigned short* Kb = Kt[t & 1];
        const unsigned short* Vb = Vt[t & 1];

        // QK^T (swapped): sacc[fk] = S^T tile, lane: q=l15, kv=fk*16+l4*4+r
        f32x4 sacc[4];
        #pragma unroll
        for (int fk = 0; fk < 4; ++fk) sacc[fk] = (f32x4){0.f, 0.f, 0.f, 0.f};
        #pragma unroll
        for (int fk = 0; fk < 4; ++fk) {
            int r = fk * 16 + l15;
            int rx = r & 7;
            #pragma unroll
            for (int c = 0; c < 8; ++c) {
                int ch = (4 * c + l4) ^ rx;
                short8 kf = *(const short8*)&Kb[r * 256 + ch * 8];
                sacc[fk] = __builtin_amdgcn_mfma_f32_16x16x32_bf16(kf, qreg[c], sacc[fk], 0, 0, 0);
            }
        }

        // online softmax (per q-row = per l15; reduce over l4 groups)
        float tm = sacc[0][0];
        #pragma unroll
        for (int fk = 0; fk < 4; ++fk)
            #pragma unroll
            for (int rr = 0; rr < 4; ++rr) tm = fmaxf(tm, sacc[fk][rr]);
        tm = fmaxf(tm, __shfl_xor(tm, 16));
        tm = fmaxf(tm, __shfl_xor(tm, 32));

        bool nomax = __all(tm <= m_r);
        float mnew = nomax ? m_r : fmaxf(m_r, tm);
        if (!nomax) {
            float corr = __expf(m_r - mnew);
            float c4[4];
            #pragma unroll
            for (int r = 0; r < 4; ++r) c4[r] = __shfl(corr, l4 * 4 + r);
            #pragma unroll
            for (int dn = 0; dn < 16; ++dn)
                #pragma unroll
                for (int r = 0; r < 4; ++r) oacc[dn][r] *= c4[r];
            l_r *= corr;
            m_r = mnew;
        }

        float p[16]; float ls = 0.f;
        #pragma unroll
        for (int fk = 0; fk < 4; ++fk)
            #pragma unroll
            for (int rr = 0; rr < 4; ++rr) {
                float e = __expf(sacc[fk][rr] - m_r);
                p[fk * 4 + rr] = e; ls += e;
            }
        ls += __shfl_xor(ls, 16);
        ls += __shfl_xor(ls, 32);
        l_r += ls;

        // pack P to bf16 pairs: W[f][pp] = kv (16f+4*l4+2pp, +1) for q=l15
        unsigned int W[4][2];
        #pragma unroll
        for (int f = 0; f < 4; ++f)
            #pragma unroll
            for (int pp = 0; pp < 2; ++pp)
                W[f][pp] = (unsigned int)f2bf(p[f * 4 + 2 * pp]) |
                           ((unsigned int)f2bf(p[f * 4 + 2 * pp + 1]) << 16);

        // gather to A-frag layout: lane q=l15, kv = c*32 + l4*8 + j
        const int sbase = l15 + ((l4 & 1) << 5);
        const bool hi = (l4 >> 1) & 1;
        #pragma unroll
        for (int kvc = 0; kvc < 2; ++kvc) {
            unsigned int a0 = (unsigned int)__shfl((int)W[2 * kvc][0], sbase);
            unsigned int a1 = (unsigned int)__shfl((int)W[2 * kvc][1], sbase);
            unsigned int a2 = (unsigned int)__shfl((int)W[2 * kvc][0], sbase + 16);
            unsigned int a3 = (unsigned int)__shfl((int)W[2 * kvc][1], sbase + 16);
            unsigned int b0 = (unsigned int)__shfl((int)W[2 * kvc + 1][0], sbase);
            unsigned int b1 = (unsigned int)__shfl((int)W[2 * kvc + 1][1], sbase);
            unsigned int b2 = (unsigned int)__shfl((int)W[2 * kvc + 1][0], sbase + 16);
            unsigned int b3 = (unsigned int)__shfl((int)W[2 * kvc + 1][1], sbase + 16);
            union { unsigned int u[4]; short8 s8; } pa;
            pa.u[0] = hi ? b0 : a0; pa.u[1] = hi ? b1 : a1;
            pa.u[2] = hi ? b2 : a2; pa.u[3] = hi ? b3 : a3;

            // PV: oacc[dn] += P[q, kv32] * V^T[d, kv32]
            #pragma unroll
            for (int dn = 0; dn < 16; ++dn) {
                int row = dn * 16 + l15;
                int ch = (kvc * 4 + l4) ^ (row & 7);
                short8 vf = *(const short8*)&Vb[row * 64 + ch * 8];
                oacc[dn] = __builtin_amdgcn_mfma_f32_16x16x32_bf16(pa.s8, vf, oacc[dn], 0, 0, 0);
            }
        }
        __builtin_amdgcn_s_barrier();
    }

    // epilogue: normalized O (bf16) + (m,l). lane: d=dn*16+l15, q=base+l4*4+r
    unsigned short* Ob = Opart + (ull)(sp * 4 + h) * NTOK * 256;
    float inv = 1.f / l_r;
    float i4[4];
    #pragma unroll
    for (int r = 0; r < 4; ++r) i4[r] = __shfl(inv, l4 * 4 + r);
    #pragma unroll
    for (int dn = 0; dn < 16; ++dn) {
        int d = dn * 16 + l15;
        #pragma unroll
        for (int r = 0; r < 4; ++r) {
            int q = qt * 128 + w * 16 + l4 * 4 + r;
            Ob[(ull)q * 256 + d] = f2bf(oacc[dn][r] * i4[r]);
        }
    }
    if (l4 == 0) {
        float2* mlp = (float2*)ml + (ull)(sp * 4 + h) * NTOK + qrow;
        *mlp = make_float2(m_r, l_r);
    }
}

// ---------------------------------------------------------------------------
// merge 2 KV-split partials (normalized bf16) -> att split pair.
// block = one q row: 4 heads x 64 lanes covering 256 d each.
__global__ __launch_bounds__(256)
void flash_combine(const unsigned short* __restrict__ Opart, const float* __restrict__ ml,
                   unsigned short* __restrict__ attH, unsigned short* __restrict__ attL)
{
    const int q = blockIdx.x;
    const int t = threadIdx.x;
    const int h = t >> 6, d4 = (t & 63) * 4;

    float2 m0 = ((const float2*)ml)[(ull)(0 * 4 + h) * NTOK + q];
    float2 m1 = ((const float2*)ml)[(ull)(1 * 4 + h) * NTOK + q];
    float ms = fmaxf(m0.x, m1.x);
    float w0 = __expf(m0.x - ms) * m0.y;
    float w1 = __expf(m1.x - ms) * m1.y;
    float inv = 1.f / (w0 + w1);
    w0 *= inv; w1 *= inv;

    ushort4 o0 = *(const ushort4*)&Opart[((ull)(0 * 4 + h) * NTOK + q) * 256 + d4];
    ushort4 o1 = *(const ushort4*)&Opart[((ull)(1 * 4 + h) * NTOK + q) * 256 + d4];
    float v0 = w0 * bf2f(o0.x) + w1 * bf2f(o1.x);
    float v1 = w0 * bf2f(o0.y) + w1 * bf2f(o1.y);
    float v2 = w0 * bf2f(o0.z) + w1 * bf2f(o1.z);
    float v3 = w0 * bf2f(o0.w) + w1 * bf2f(o1.w);

    ull ai = (ull)q * EMB + h * 256 + d4;
    ushort4 ho, lo;
    ho.x = f2bf(v0); lo.x = f2bf(v0 - bf2f(ho.x));
    ho.y = f2bf(v1); lo.y = f2bf(v1 - bf2f(ho.y));
    ho.z = f2bf(v2); lo.z = f2bf(v2 - bf2f(ho.z));
    ho.w = f2bf(v3); lo.w = f2bf(v3 - bf2f(ho.w));
    *(ushort4*)&attH[ai] = ho;
    *(ushort4*)&attL[ai] = lo;
}

// ---------------------------------------------------------------------------
template<bool F32IN>
__global__ __launch_bounds__(256)
void l2norm_rows(const float* __restrict__ inF, const unsigned short* __restrict__ inH,
                 const unsigned short* __restrict__ inL,
                 unsigned short* __restrict__ oH, unsigned short* __restrict__ oL)
{
    const ull row = blockIdx.x;
    const int t = threadIdx.x;
    const int lane = t & 63, wid = t >> 6;
    __shared__ float red[4];

    float v[4];
    if constexpr (F32IN) {
        float4 x = *(const float4*)&inF[row * EMB + t * 4];
        v[0] = x.x; v[1] = x.y; v[2] = x.z; v[3] = x.w;
    } else {
        ushort4 hh = *(const ushort4*)&inH[row * EMB + t * 4];
        ushort4 ll = *(const ushort4*)&inL[row * EMB + t * 4];
        v[0] = bf2f(hh.x) + bf2f(ll.x); v[1] = bf2f(hh.y) + bf2f(ll.y);
        v[2] = bf2f(hh.z) + bf2f(ll.z); v[3] = bf2f(hh.w) + bf2f(ll.w);
    }
    float ss = v[0] * v[0] + v[1] * v[1] + v[2] * v[2] + v[3] * v[3];
    #pragma unroll
    for (int o = 32; o > 0; o >>= 1) ss += __shfl_down(ss, o);
    if (lane == 0) red[wid] = ss;
    __syncthreads();
    ss = red[0] + red[1] + red[2] + red[3];

    float inv = 1.f / fmaxf(sqrtf(ss), 1e-8f);
    ushort4 ho, lo;
    float s0 = v[0] * inv, s1 = v[1] * inv, s2 = v[2] * inv, s3 = v[3] * inv;
    ho.x = f2bf(s0); lo.x = f2bf(s0 - bf2f(ho.x));
    ho.y = f2bf(s1); lo.y = f2bf(s1 - bf2f(ho.y));
    ho.z = f2bf(s2); lo.z = f2bf(s2 - bf2f(ho.z));
    ho.w = f2bf(s3); lo.w = f2bf(s3 - bf2f(ho.w));
    *(ushort4*)&oH[row * EMB + t * 4] = ho;
    *(ushort4*)&oL[row * EMB + t * 4] = lo;
}

__global__ __launch_bounds__(256)
void add_pos_pair(const float* __restrict__ in, const float* __restrict__ pos,
                  unsigned short* __restrict__ oH, unsigned short* __restrict__ oL)
{
    ull i = ((ull)blockIdx.x * 256 + threadIdx.x) * 4;
    float4 a = *(const float4*)&in[i];
    float4 p = *(const float4*)&pos[(int)(i & (EMB - 1))];
    float w[4] = { a.x + p.x, a.y + p.y, a.z + p.z, a.w + p.w };
    ushort4 ho, lo;
    ho.x = f2bf(w[0]); lo.x = f2bf(w[0] - bf2f(ho.x));
    ho.y = f2bf(w[1]); lo.y = f2bf(w[1] - bf2f(ho.y));
    ho.z = f2bf(w[2]); lo.z = f2bf(w[2] - bf2f(ho.z));
    ho.w = f2bf(w[3]); lo.w = f2bf(w[3] - bf2f(ho.w));
    *(ushort4*)&oH[i] = ho;
    *(ushort4*)&oL[i] = lo;
}

__global__ __launch_bounds__(256)
void split_pair(const float* __restrict__ in, unsigned short* __restrict__ oH,
                unsigned short* __restrict__ oL)
{
    ull i = ((ull)blockIdx.x * 256 + threadIdx.x) * 4;
    float4 a = *(const float4*)&in[i];
    float w[4] = { a.x, a.y, a.z, a.w };
    ushort4 ho, lo;
    ho.x = f2bf(w[0]); lo.x = f2bf(w[0] - bf2f(ho.x));
    ho.y = f2bf(w[1]); lo.y = f2bf(w[1] - bf2f(ho.y));
    ho.z = f2bf(w[2]); lo.z = f2bf(w[2] - bf2f(ho.z));
    ho.w = f2bf(w[3]); lo.w = f2bf(w[3] - bf2f(ho.w));
    *(ushort4*)&oH[i] = ho;
    *(ushort4*)&oL[i] = lo;
}

// transpose bf16 [4096][ld] block cols -> out [1024][4096]
__global__ __launch_bounds__(256)
void transpose_bf16(const unsigned short* __restrict__ in, int ld,
                    unsigned short* __restrict__ out) {
    __shared__ unsigned short tile[64][65];
    const int bx = blockIdx.x * 64;
    const int by = blockIdx.y * 64;
    const int t = threadIdx.x;
    #pragma unroll
    for (int i = 0; i < 16; ++i) {
        int idx = i * 256 + t;
        int r = idx >> 6, c = idx & 63;
        tile[r][c] = in[(ull)(by + r) * ld + bx + c];
    }
    __syncthreads();
    #pragma unroll
    for (int i = 0; i < 16; ++i) {
        int idx = i * 256 + t;
        int r = idx >> 6, c = idx & 63;
        out[(ull)(bx + r) * 4096 + by + c] = tile[c][r];
    }
}

// ---------------------------------------------------------------------------
namespace {

template<int S, int O>
inline void G(dim3 grid,
              const unsigned short* Ah, const unsigned short* Al, int lda, ull sAz,
              const unsigned short* Bh, const unsigned short* Bl, int ldb, ull sBz,
              void* Ch, void* Cl, int ldc, ull sCz,
              int K, float alpha, const float* bias,
              const unsigned short* rh, const unsigned short* rl, int rm, hipStream_t st)
{
    gemm_mfma<S, O><<<grid, dim3(256), 0, st>>>(Ah, Al, lda, sAz, Bh, Bl, ldb, sBz,
                                                Ch, Cl, ldc, sCz, K, alpha, bias, rh, rl, rm);
}

struct Bufs {
    unsigned short *Ph[6], *Pl[6];
    unsigned short *ATTh, *ATTl, *QKV, *VT, *Wih, *Wil, *Woh, *Wol, *Opart;
    float *ml;
};

void run_mha(const unsigned short* qh, const unsigned short* ql,
             const unsigned short* kh, const unsigned short* kl,
             const float* in_w, const float* in_b,
             const float* out_w, const float* out_b,
             unsigned short* dsth, unsigned short* dstl,
             const unsigned short* resh, const unsigned short* resl, int resMode,
             const Bufs& B, bool convW, hipStream_t s)
{
    const ull EE = (ull)EMB * EMB;
    if (convW) {
        split_pair<<<3 * EE / 1024, 256, 0, s>>>(in_w, B.Wih, B.Wil);
        split_pair<<<EE / 1024, 256, 0, s>>>(out_w, B.Woh, B.Wol);
    }
    // Q proj -> QKV[:, 0:1024]; fused KV proj -> QKV[:, 1024:3072]
    G<3, 1>(dim3(8, 32), qh, ql, EMB, 0, B.Wih, B.Wil, EMB, 0,
            B.QKV, nullptr, 3072, 0, EMB, 1.f, in_b, nullptr, nullptr, 0, s);
    G<3, 1>(dim3(16, 32), kh, kl, EMB, 0, B.Wih + EE, B.Wil + EE, EMB, 0,
            B.QKV + 1024, nullptr, 3072, 0, EMB, 1.f, in_b + EMB, nullptr, nullptr, 0, s);
    transpose_bf16<<<dim3(16, 64), 256, 0, s>>>(B.QKV + 2048, 3072, B.VT);

    flash_attn<<<dim3(32, 2, 4), 512, 0, s>>>(B.QKV, B.VT, B.Opart, B.ml);
    flash_combine<<<NTOK, 256, 0, s>>>(B.Opart, B.ml, B.ATTh, B.ATTl);

    G<3, 2>(dim3(EMB / 128, NTOK / 128), B.ATTh, B.ATTl, EMB, 0, B.Woh, B.Wol, EMB, 0,
            dsth, dstl, EMB, 0, EMB, 1.f, out_b, resh, resl, resMode, s);
}

} // namespace

extern "C" void kernel_launch(void* const* d_in, const int* in_sizes, int n_in,
                              void* d_out, int out_size, void* d_ws, size_t ws_size,
                              hipStream_t stream) {
    const float* local_feat  = (const float*)d_in[0];
    const float* global_feat = (const float*)d_in[1];
    const float* text_feat   = (const float*)d_in[2];
    const float* pos_l       = (const float*)d_in[3];
    const float* pos_g       = (const float*)d_in[4];
    const float* fc_w        = (const float*)d_in[5];
    const float* fc_b        = (const float*)d_in[6];
    const float* lg_in_w     = (const float*)d_in[7];
    const float* lg_in_b     = (const float*)d_in[8];
    const float* lg_out_w    = (const float*)d_in[9];
    const float* lg_out_b    = (const float*)d_in[10];
    const float* vt_in_w     = (const float*)d_in[11];
    const float* vt_in_b     = (const float*)d_in[12];
    const float* vt_out_w    = (const float*)d_in[13];
    const float* vt_out_b    = (const float*)d_in[14];
    const float* ml_in_w     = (const float*)d_in[15];
    const float* ml_in_b     = (const float*)d_in[16];
    const float* ml_out_w    = (const float*)d_in[17];
    const float* ml_out_b    = (const float*)d_in[18];
    float* out = (float*)d_out;

    const ull TE = (ull)NTOK * EMB;
    unsigned short* w = (unsigned short*)d_ws;
    Bufs B;
    for (int i = 0; i < 6; ++i) { B.Ph[i] = w + (2 * i) * TE; B.Pl[i] = w + (2 * i + 1) * TE; }
    B.ATTh = w + 12 * TE; B.ATTl = w + 13 * TE;
    B.QKV  = w + 14 * TE;               // 3 TE
    B.VT   = w + 17 * TE;               // 1 TE
    B.Opart = w + 18 * TE;              // 2 TE (bf16, 2 splits x 4 heads)
    B.ml    = (float*)(w + 22 * TE);    // 256 KB
    B.Wih = w + 26 * TE; B.Wil = B.Wih + 3 * (ull)EMB * EMB;
    B.Woh = B.Wil + 3 * (ull)EMB * EMB; B.Wol = B.Woh + (ull)EMB * EMB;

    add_pos_pair<<<TE / 1024, 256, 0, stream>>>(local_feat, pos_l, B.Ph[0], B.Pl[0]);
    add_pos_pair<<<TE / 1024, 256, 0, stream>>>(global_feat, pos_g, B.Ph[1], B.Pl[1]);

    // tf = text @ fc_w^T + fc_b -> P2 (text split staged in ATT pair)
    split_pair<<<TE / 1024, 256, 0, stream>>>(text_feat, B.ATTh, B.ATTl);
    split_pair<<<(ull)EMB * EMB / 1024, 256, 0, stream>>>(fc_w, B.Wih, B.Wil);
    G<3, 2>(dim3(EMB / 128, NTOK / 128), B.ATTh, B.ATTl, EMB, 0, B.Wih, B.Wil, EMB, 0,
            B.Ph[2], B.Pl[2], EMB, 0, EMB, 1.f, fc_b, nullptr, nullptr, 0, stream);

    run_mha(B.Ph[0], B.Pl[0], B.Ph[1], B.Pl[1], lg_in_w, lg_in_b, lg_out_w, lg_out_b,
            B.Ph[3], B.Pl[3], B.Ph[0], B.Pl[0], 1, B, true, stream);
    run_mha(B.Ph[2], B.Pl[2], B.Ph[0], B.Pl[0], vt_in_w, vt_in_b, vt_out_w, vt_out_b,
            B.Ph[4], B.Pl[4], B.Ph[0], B.Pl[0], 1, B, true, stream);
    run_mha(B.Ph[2], B.Pl[2], B.Ph[1], B.Pl[1], vt_in_w, vt_in_b, vt_out_w, vt_out_b,
            B.Ph[5], B.Pl[5], B.Ph[2], B.Pl[2], 1, B, false, stream);
    run_mha(B.Ph[3], B.Pl[3], B.Ph[5], B.Pl[5], ml_in_w, ml_in_b, ml_out_w, ml_out_b,
            B.Ph[0], B.Pl[0], nullptr, nullptr, 0, B, true, stream);
    run_mha(B.Ph[4], B.Pl[4], B.Ph[3], B.Pl[3], ml_in_w, ml_in_b, ml_out_w, ml_out_b,
            B.Ph[1], B.Pl[1], nullptr, nullptr, 0, B, false, stream);
    run_mha(B.Ph[1], B.Pl[1], B.Ph[0], B.Pl[0], ml_in_w, ml_in_b, ml_out_w, ml_out_b,
            B.Ph[3], B.Pl[3], nullptr, nullptr, 0, B, false, stream);
    run_mha(B.Ph[2], B.Pl[2], B.Ph[3], B.Pl[3], ml_in_w, ml_in_b, ml_out_w, ml_out_b,
            B.Ph[4], B.Pl[4], B.Ph[2], B.Pl[2], 2, B, false, stream);

    l2norm_rows<false><<<NTOK, 256, 0, stream>>>(nullptr, B.Ph[4], B.Pl[4], B.Ph[4], B.Pl[4]);
    l2norm_rows<true ><<<NTOK, 256, 0, stream>>>(local_feat, nullptr, nullptr, B.Ph[5], B.Pl[5]);

    G<3, 0>(dim3(QTY / 128, QTY / 128, 8),
            B.Ph[4], B.Pl[4], EMB, (ull)QTY * EMB,
            B.Ph[5], B.Pl[5], EMB, (ull)QTY * EMB,
            out, nullptr, QTY, (ull)QTY * QTY,
            EMB, 1.f, nullptr, nullptr, nullptr, 0, stream);
}